// Round 9
// baseline (437.992 us; speedup 1.0000x reference)
//
#include <hip/hip_runtime.h>

// Problem constants (fixed by the reference: x,y are (3000, 800, 8) f32)
#define NT   3000          // time samples per trace
#define NK   2999          // NT-1 (cdf length)
#define NTR  6400          // traces (800*8); trace n element t at X[t*NTR+n]
#define TRIW 4498500.0f    // sum_{i=1..2999} i
#define FINF 3.4e38f

#define TSTR 3008          // padded per-trace row stride (floats) = 47*64
#define CB   47            // 64-wide time chunks per trace
#define GT   64            // traces per kB2 block
#define NPART 1175         // kC3 blocks = 25 * 47

// monotone float<->uint map for atomicMin on signed floats
__device__ __forceinline__ unsigned fmap(float f) {
    unsigned u = __float_as_uint(f);
    return (u & 0x80000000u) ? ~u : (u | 0x80000000u);
}
__device__ __forceinline__ float funmap(unsigned u) {
    u = (u & 0x80000000u) ? (u & 0x7FFFFFFFu) : ~u;
    return __uint_as_float(u);
}

// ---------------------------------------------------------------------------
// kT: LDS-tiled pass over both arrays. For Y (z=1): transposed write of the
// trapezoid midpoints s[j]=0.5(a[j]+a[j+1]) into [trace][time] rows (sTy).
// For both: per-(chunk,trace) sum of s, weighted sum s*(NK-j) (atomicAdd to
// per-trace), and chunk min of a (atomicMin, sortable-uint). No cross-lane ops.
// grid (100 n-tiles, 47 j-tiles, 2 arrays), 256 threads.
// ---------------------------------------------------------------------------
__global__ __launch_bounds__(256) void kT(
    const float* __restrict__ X, const float* __restrict__ Y,
    float* __restrict__ sTy,
    float* __restrict__ ssx, float* __restrict__ ssy,
    float* __restrict__ wsxA, float* __restrict__ wsyA,
    unsigned* __restrict__ mnUx, unsigned* __restrict__ mnUy)
{
    __shared__ float t[65][65];        // [j-row][trace-col]
    __shared__ float pS[4][GT], pW[4][GT], pM[4][GT];
    const int lane = threadIdx.x & 63;
    const int wv   = threadIdx.x >> 6;
    const int n0 = blockIdx.x * 64;
    const int j0 = blockIdx.y * 64;
    const int z  = blockIdx.z;
    const float* __restrict__ src = z ? Y : X;
    float* __restrict__ ssA = z ? ssy : ssx;
    float* __restrict__ wA  = z ? wsyA : wsxA;
    unsigned* __restrict__ mU = z ? mnUy : mnUx;

    // load 65 a-rows (coalesced: lane = trace)
    #pragma unroll
    for (int i = 0; i < 17; ++i) {
        const int r = wv + 4 * i;
        if (r < 65) {
            const int jr = j0 + r;
            if (jr < NT) t[r][lane] = src[(size_t)jr * NTR + n0 + lane];
        }
    }
    __syncthreads();

    // transposed write of s rows (Y only): lane = time, contiguous per row
    if (z) {
        const int j = j0 + lane;
        const bool vs = (j < NK);
        for (int rr = 0; rr < 16; ++rr) {
            const int row = wv * 16 + rr;  // local trace
            const float a0 = t[lane][row];
            const float a1 = t[lane + 1][row];
            sTy[(size_t)(n0 + row) * TSTR + j0 + lane] = vs ? 0.5f * (a0 + a1) : 0.f;
        }
    }

    // stats: lane = trace, serial over this wave's 16 time rows
    {
        const int r0 = wv * 16;
        float sum = 0.f, wsum = 0.f, mn = FINF;
        float aprev = t[r0][lane];
        #pragma unroll 4
        for (int rr = 0; rr < 16; ++rr) {
            const int jr = j0 + r0 + rr;
            const float anext = t[r0 + rr + 1][lane];
            if (jr < NT) mn = fminf(mn, aprev);
            if (jr < NK) {
                const float s = 0.5f * (aprev + anext);
                sum += s;
                wsum = fmaf(s, (float)(NK - jr), wsum);
            }
            aprev = anext;
        }
        pS[wv][lane] = sum; pW[wv][lane] = wsum; pM[wv][lane] = mn;
    }
    __syncthreads();
    if (threadIdx.x < GT) {
        const int l = threadIdx.x;
        const float S = pS[0][l] + pS[1][l] + pS[2][l] + pS[3][l];
        const float W = pW[0][l] + pW[1][l] + pW[2][l] + pW[3][l];
        const float M = fminf(fminf(pM[0][l], pM[1][l]), fminf(pM[2][l], pM[3][l]));
        ssA[blockIdx.y * NTR + n0 + l] = S;
        atomicAdd(&wA[n0 + l], W);
        atomicMin(&mU[n0 + l], fmap(M));
    }
}

// ---------------------------------------------------------------------------
// kB2: per-trace finalize: mind/S from atomics, exclusive scans of chunk sums
// (in place -> raw-cdf chunk offsets), and per-(chunk,trace) conservative obs
// start chunk qstA[c] = largest q with obsbnd'(q) < synbnd_excl'(c), via a
// two-pointer over the 47+47 chunk boundary values. 100 blocks x 256.
// ---------------------------------------------------------------------------
__global__ __launch_bounds__(256) void kB2(
    float* __restrict__ ssx, float* __restrict__ ssy,
    const float* __restrict__ wsxA, const float* __restrict__ wsyA,
    const unsigned* __restrict__ mnUx, const unsigned* __restrict__ mnUy,
    float* __restrict__ mindA, float* __restrict__ SsA, float* __restrict__ SoA,
    unsigned char* __restrict__ qstA)
{
    __shared__ float tA[CB][GT + 1];
    __shared__ float tB[CB][GT + 1];
    const int n0 = blockIdx.x * GT;
    const int tid = threadIdx.x, lane = tid & 63, crow = tid >> 6;

    for (int c = crow; c < CB; c += 4) {
        tA[c][lane] = ssx[c * NTR + n0 + lane];
        tB[c][lane] = ssy[c * NTR + n0 + lane];
    }
    __syncthreads();

    if (tid < GT) {
        const float mn = fminf(funmap(mnUx[n0 + tid]), funmap(mnUy[n0 + tid]));
        const float Ss = wsxA[n0 + tid] - mn * TRIW;
        const float So = wsyA[n0 + tid] - mn * TRIW;
        mindA[n0 + tid] = mn; SsA[n0 + tid] = Ss; SoA[n0 + tid] = So;

        float rx = 0.f, ry = 0.f;
        for (int c = 0; c < CB; ++c) {
            const float tx = tA[c][tid], ty = tB[c][tid];
            tA[c][tid] = rx; tB[c][tid] = ry;
            rx += tx; ry += ty;
        }
        // conservative obs start chunk per syn chunk (two-pointer, both monotone)
        int q = 0;
        qstA[n0 + tid] = 0;                        // c = 0
        for (int c = 1; c < CB; ++c) {
            const float tgt = (tA[c][tid] - (float)(c * 64) * mn) * So;
            while (q + 1 < CB) {
                const float ov = (tB[q + 1][tid] - (float)((q + 1) * 64) * mn) * Ss;
                if (ov < tgt) ++q; else break;
            }
            qstA[c * NTR + n0 + tid] = (unsigned char)q;
        }
    }
    __syncthreads();
    for (int c = crow; c < CB; c += 4) {          // write back exclusive scans
        ssx[c * NTR + n0 + lane] = tA[c][lane];
        ssy[c * NTR + n0 + lane] = tB[c][lane];
    }
}

// ---------------------------------------------------------------------------
// kC3: thread per (trace n, 64-chunk c). Syn CDF streamed from X (coalesced
// across lanes: same k, consecutive n). Obs CDF walked serially in this
// trace's contiguous sTy row (per-lane L1-resident, 16 elems per cache line),
// starting at the precomputed conservative chunk. No LDS / shfl in hot loop.
// grid (25, 47) x 256.
// ---------------------------------------------------------------------------
__global__ __launch_bounds__(256) void kC3(
    const float* __restrict__ X, const float* __restrict__ sTy,
    const float* __restrict__ ssxS, const float* __restrict__ ssyS,
    const float* __restrict__ mindA, const float* __restrict__ SsA,
    const float* __restrict__ SoA, const unsigned char* __restrict__ qstA,
    float* __restrict__ partial)
{
    const int n = blockIdx.x * 256 + threadIdx.x;
    const int c = blockIdx.y;
    const int j0 = c * 64;
    const int j1 = min(NK, j0 + 64);

    const float mind = mindA[n];
    const float Ss = SsA[n];
    const float So = SoA[n];

    float cs = ssxS[c * NTR + n];                  // raw syn cumsum through j0-1
    float xp = X[(size_t)j0 * NTR + n];

    const float* __restrict__ syr = sTy + (size_t)n * TSTR;
    int m;                                         // obs cursor (idx candidate)
    float cy;                                      // raw obs cumsum through m
    {
        const int q = (int)qstA[c * NTR + n];
        m = q * 64;                                // q <= 46 -> m <= 2944 < NK
        cy = ssyS[q * NTR + n] + syr[m];
    }

    float acc = 0.f;
    for (int k = j0; k < j1; ++k) {
        const float xn = X[(size_t)(k + 1) * NTR + n];
        cs += 0.5f * (xp + xn); xp = xn;
        const float synp = cs - (float)(k + 1) * mind;   // cdf'_syn[k]
        const float target = synp * So;
        // advance while obs'[m] < target (cross-multiplied); idx = m at exit
        while (m < NK && (cy - (float)(m + 1) * mind) * Ss < target) {
            ++m;
            cy += syr[m];                          // pad reads (m==NK) are 0
        }
        const float diff = (float)(k + 1 - m);
        acc = fmaf(diff * diff, synp, acc);
    }
    acc /= Ss;

    __shared__ float red[256];
    red[threadIdx.x] = acc;
    __syncthreads();
    for (int s = 128; s > 0; s >>= 1) {
        if (threadIdx.x < s) red[threadIdx.x] += red[threadIdx.x + s];
        __syncthreads();
    }
    if (threadIdx.x == 0) partial[blockIdx.y * 25 + blockIdx.x] = red[0];
}

// kD: reduce block partials -> out[0]
__global__ __launch_bounds__(256) void kD(
    const float* __restrict__ partial, float* __restrict__ out)
{
    float v = 0.f;
    for (int i = threadIdx.x; i < NPART; i += 256) v += partial[i];
    __shared__ float red[256];
    red[threadIdx.x] = v;
    __syncthreads();
    for (int s = 128; s > 0; s >>= 1) {
        if (threadIdx.x < s) red[threadIdx.x] += red[threadIdx.x + s];
        __syncthreads();
    }
    if (threadIdx.x == 0) out[0] = red[0];
}

// ---------------------------------------------------------------------------
extern "C" void kernel_launch(void* const* d_in, const int* in_sizes, int n_in,
                              void* d_out, int out_size, void* d_ws, size_t ws_size,
                              hipStream_t stream)
{
    const float* X = (const float*)d_in[0];
    const float* Y = (const float*)d_in[1];
    float* out = (float*)d_out;

    float* w = (float*)d_ws;
    float* sTy  = w;                               // NTR*TSTR floats (77 MB)
    float* ssx  = sTy + (size_t)NTR * TSTR;        // CB*NTR (chunk sums -> scans)
    float* ssy  = ssx + CB * NTR;
    float* wsxA = ssy + CB * NTR;                  // [2*NTR] zeroed
    float* wsyA = wsxA + NTR;
    unsigned* mnU = (unsigned*)(wsyA + NTR);       // [2*NTR] set to 0xFF
    float* mindA = (float*)(mnU + 2 * NTR);
    float* SsA   = mindA + NTR;
    float* SoA   = SsA + NTR;
    float* partial = SoA + NTR;                    // [2048]
    unsigned char* qstA = (unsigned char*)(partial + 2048);  // [CB*NTR] bytes
    // total ~ 81 MB (well under the >=157 MB proven available in R6/R7)

    hipMemsetAsync(wsxA, 0, 2 * NTR * sizeof(float), stream);
    hipMemsetAsync(mnU, 0xFF, 2 * NTR * sizeof(unsigned), stream);

    kT<<<dim3(100, 47, 2), 256, 0, stream>>>(X, Y, sTy, ssx, ssy,
                                             wsxA, wsyA, mnU, mnU + NTR);
    kB2<<<100, 256, 0, stream>>>(ssx, ssy, wsxA, wsyA, mnU, mnU + NTR,
                                 mindA, SsA, SoA, qstA);
    kC3<<<dim3(25, 47), 256, 0, stream>>>(X, sTy, ssx, ssy,
                                          mindA, SsA, SoA, qstA, partial);
    kD<<<1, 256, 0, stream>>>(partial, out);
}